// Round 10
// baseline (120.562 us; speedup 1.0000x reference)
//
#include <hip/hip_runtime.h>
#include <math.h>

// Problem constants
#define MAT 16384            // D*D
// Workspace float offsets
#define OFF_MC   0                        // M  interleaved [i][p][2]  (32768 f)
#define OFF_MTC  32768                    // M^T interleaved [k][j][2] (32768 f)
#define OFF_UVTC 65536                    // Uv^T interleaved [k][j][2]
#define OFF_ZSR  2129920                  // Zs = Z^T, [kk*16+b][j][i]
#define OFF_ZSI  (OFF_ZSR + 32*16384)
#define OFF_VR   (OFF_ZSI + 32*16384)     // V natural [t*16+b][i][j]
#define OFF_VI   (OFF_VR + 32*16384)
#define OFF_TR   (OFF_VI + 32*16384)      // tr[q][kk][b][2]
#define OFF_S    (OFF_TR + 2048)          // s[q][kk][b]

#define RLF(x, l) __int_as_float(__builtin_amdgcn_readlane(__float_as_int(x), (l)))

__device__ __forceinline__ float dot4(float4 a, float4 b) {
    return a.x*b.x + a.y*b.y + a.z*b.z + a.w*b.w;
}

// ---------------- Kernel 1: M = Uq^H * Uk + interleaved planes ----------------
__global__ __launch_bounds__(128) void k_M(const float* __restrict__ Uq,
                                           const float* __restrict__ Uk,
                                           const float* __restrict__ Uv,
                                           float* __restrict__ ws) {
    const int i = blockIdx.x;
    const int j = threadIdx.x;
    __shared__ float qr_s[128], qi_s[128];
    qr_s[j] = Uq[(j*128 + i)*2 + 0];   // Uq[p=j, i]
    qi_s[j] = Uq[(j*128 + i)*2 + 1];
    __syncthreads();
    const float2* Uk2 = (const float2*)Uk;
    float mr = 0.f, mi = 0.f;
    #pragma unroll 8
    for (int p = 0; p < 128; ++p) {
        float2 k2 = Uk2[p*128 + j];
        float qr = qr_s[p], qi = qi_s[p];
        mr += qr*k2.x + qi*k2.y;       // conj(Uq[p,i]) * Uk[p,j]
        mi += qr*k2.y - qi*k2.x;
    }
    ws[OFF_MC  + i*256 + 2*j]     = mr;   // M[i][j] interleaved
    ws[OFF_MC  + i*256 + 2*j + 1] = mi;
    ws[OFF_MTC + j*256 + 2*i]     = mr;   // M^T[j][i] interleaved
    ws[OFF_MTC + j*256 + 2*i + 1] = mi;
    float2 uv = ((const float2*)Uv)[i*128 + j];
    ws[OFF_UVTC + j*256 + 2*i]     = uv.x; // Uv^T
    ws[OFF_UVTC + j*256 + 2*i + 1] = uv.y;
}

// ---------------- Kernel 2: fused two-sided evolve Z = U X U^H (v5) ----------------
// grid 512: m = bid&63 (XCD = m%8), strip i0 = (bid>>6)*16. 256 thr = 4 waves.
// Wave wv owns rows r0 = i0+wv*4 .. +3. Lane L owns cols {2L, 2L+1}.
// NO LDS in main loops:
//   A-strip in VGPRs: a[16] per lane, lane L holds p=2L,2L+1 (g=(p&1)*8+r*2+c);
//     per-pp broadcast via v_readlane (VALU pipe).
//   B direct global->VGPR (each col owned by 1 lane; X L2-hot via XCD grouping).
//   Phase-1 acc y[16] IS phase-2's A operand (register renaming, no movement).
// Barriers only in the m<32 Z^T-transpose epilogue.
__global__ __launch_bounds__(256) void k_fused(const float* __restrict__ xr,
                                               const float* __restrict__ xi,
                                               const float* __restrict__ Uv,
                                               float* __restrict__ ws) {
    const int bid = blockIdx.x;
    const int m   = bid & 63;
    const int i0  = (bid >> 6) * 16;
    const int tid = threadIdx.x;
    const int wv  = tid >> 6;
    const int L   = tid & 63;
    const int r0  = i0 + wv*4;
    const int cbase = 2*L;

    __shared__ __align__(16) float T[2*16*132];   // epilogue transpose only

    // ---- A preload: 4 x float4, fully coalesced ----
    const float* Ap = (m < 32) ? (ws + OFF_MC) : Uv;   // [row][p][2]
    float a[16];
    #pragma unroll
    for (int r = 0; r < 4; ++r) {
        float4 v = *(const float4*)&Ap[(r0 + r)*256 + 4*L];
        a[r*2]     = v.x; a[r*2+1]   = v.y;    // p = 2L
        a[8+r*2]   = v.z; a[8+r*2+1] = v.w;    // p = 2L+1
    }

    float y[16];
    #pragma unroll
    for (int g = 0; g < 16; ++g) y[g] = 0.f;

    const float* Xr = xr + (m & 31)*MAT;
    const float* Xi = xi + (m & 31)*MAT;

    float2 Ar0, Ai0, Ar1, Ai1, Br0, Bi0, Br1, Bi1;
#define LD1(PP, R0, I0, R1, I1) do { int _p = (PP);          \
    R0 = *(const float2*)&Xr[_p*128 + cbase];                \
    I0 = *(const float2*)&Xi[_p*128 + cbase];                \
    R1 = *(const float2*)&Xr[(_p+1)*128 + cbase];            \
    I1 = *(const float2*)&Xi[(_p+1)*128 + cbase]; } while(0)

#define STEP1(IT, R0, I0, R1, I1) do {                       \
    float s[16];                                             \
    _Pragma("unroll")                                        \
    for (int g = 0; g < 16; ++g) s[g] = RLF(a[g], (IT));     \
    _Pragma("unroll")                                        \
    for (int r = 0; r < 4; ++r) {                            \
        float ar = s[r*2], ai = s[r*2+1];                    \
        y[r*2]     += ar*R0.x - ai*I0.x;                     \
        y[r*2+1]   += ar*I0.x + ai*R0.x;                     \
        y[8+r*2]   += ar*R0.y - ai*I0.y;                     \
        y[8+r*2+1] += ar*I0.y + ai*R0.y;                     \
        float br = s[8+r*2], bi = s[8+r*2+1];                \
        y[r*2]     += br*R1.x - bi*I1.x;                     \
        y[r*2+1]   += br*I1.x + bi*R1.x;                     \
        y[8+r*2]   += br*R1.y - bi*I1.y;                     \
        y[8+r*2+1] += br*I1.y + bi*R1.y;                     \
    } } while(0)

    // ================= Phase 1: Y = U * X =================
    LD1(0, Ar0,Ai0,Ar1,Ai1);
    LD1(2, Br0,Bi0,Br1,Bi1);
    #pragma unroll 1
    for (int it = 0; it < 64; it += 2) {
        STEP1(it, Ar0,Ai0,Ar1,Ai1);
        { int p = 2*it+4; if (p > 126) p = 126; LD1(p, Ar0,Ai0,Ar1,Ai1); }
        STEP1(it+1, Br0,Bi0,Br1,Bi1);
        { int p = 2*it+6; if (p > 126) p = 126; LD1(p, Br0,Bi0,Br1,Bi1); }
    }

    // ================= Phase 2: Z = Y * U^H =================
    float z[16];
    #pragma unroll
    for (int g = 0; g < 16; ++g) z[g] = 0.f;
    const float4* UT4 = (const float4*)(ws + (m < 32 ? OFF_MTC : OFF_UVTC));

    float4 Ue, Uo, Ve, Vo;
#define LD2(KK, E, O) do { int _k = (KK);                    \
    E = UT4[_k*64 + L]; O = UT4[(_k+1)*64 + L]; } while(0)

#define STEP2(IT, E, O) do {                                 \
    float s[16];                                             \
    _Pragma("unroll")                                        \
    for (int g = 0; g < 16; ++g) s[g] = RLF(y[g], (IT));     \
    _Pragma("unroll")                                        \
    for (int r = 0; r < 4; ++r) {                            \
        float yr = s[r*2], yi = s[r*2+1];                    \
        z[r*2]     += yr*E.x + yi*E.y;                       \
        z[r*2+1]   += yi*E.x - yr*E.y;                       \
        z[8+r*2]   += yr*E.z + yi*E.w;                       \
        z[8+r*2+1] += yi*E.z - yr*E.w;                       \
        float wr = s[8+r*2], wi = s[8+r*2+1];                \
        z[r*2]     += wr*O.x + wi*O.y;                       \
        z[r*2+1]   += wi*O.x - wr*O.y;                       \
        z[8+r*2]   += wr*O.z + wi*O.w;                       \
        z[8+r*2+1] += wi*O.z - wr*O.w;                       \
    } } while(0)

    LD2(0, Ue, Uo);
    LD2(2, Ve, Vo);
    #pragma unroll 1
    for (int it = 0; it < 64; it += 2) {
        STEP2(it, Ue, Uo);
        { int k = 2*it+4; if (k > 126) k = 126; LD2(k, Ue, Uo); }
        STEP2(it+1, Ve, Vo);
        { int k = 2*it+6; if (k > 126) k = 126; LD2(k, Ve, Vo); }
    }

    // ================= Epilogue =================
    if (m < 32) {
        float* T_r = T;                  // [16][132]
        float* T_i = T + 16*132;
        #pragma unroll
        for (int r = 0; r < 4; ++r) {
            int ii = wv*4 + r;
            *(float2*)&T_r[ii*132 + cbase] = make_float2(z[r*2],   z[8+r*2]);
            *(float2*)&T_i[ii*132 + cbase] = make_float2(z[r*2+1], z[8+r*2+1]);
        }
        __syncthreads();
        float* dstR = ws + OFF_ZSR + m*MAT;
        float* dstI = ws + OFF_ZSI + m*MAT;
        #pragma unroll
        for (int w = 0; w < 8; ++w) {
            int o  = w*256 + tid;        // 0..2047
            int c  = o >> 4;             // col j 0..127
            int ii = o & 15;             // row-in-strip
            dstR[c*128 + i0 + ii] = T_r[ii*132 + c];
            dstI[c*128 + i0 + ii] = T_i[ii*132 + c];
        }
    } else {
        float* dstR = ws + OFF_VR + (m-32)*MAT;
        float* dstI = ws + OFF_VI + (m-32)*MAT;
        #pragma unroll
        for (int r = 0; r < 4; ++r) {
            *(float2*)&dstR[(r0 + r)*128 + cbase] = make_float2(z[r*2],   z[8+r*2]);
            *(float2*)&dstI[(r0 + r)*128 + cbase] = make_float2(z[r*2+1], z[8+r*2+1]);
        }
    }
#undef LD1
#undef STEP1
#undef LD2
#undef STEP2
}

// ---------------- Kernel 3: tr[q,kk,b] = sum X_qb .* Zs_kkb (complex) ----------------
__global__ __launch_bounds__(256) void k_trace(const float* __restrict__ xr,
                                               const float* __restrict__ xi,
                                               float* __restrict__ ws) {
    const int q = blockIdx.x >> 4, b = blockIdx.x & 15;
    const int tid = threadIdx.x;
    const float4* Xr4  = (const float4*)(xr + (q*16 + b)*MAT);
    const float4* Xi4  = (const float4*)(xi + (q*16 + b)*MAT);
    const float4* Z0r4 = (const float4*)(ws + OFF_ZSR + b*MAT);
    const float4* Z0i4 = (const float4*)(ws + OFF_ZSI + b*MAT);
    const float4* Z1r4 = (const float4*)(ws + OFF_ZSR + (16+b)*MAT);
    const float4* Z1i4 = (const float4*)(ws + OFF_ZSI + (16+b)*MAT);
    float r0 = 0.f, s0 = 0.f, r1 = 0.f, s1 = 0.f;
    #pragma unroll 4
    for (int w = 0; w < 16; ++w) {
        int e = w*256 + tid;
        float4 xrv = Xr4[e], xiv = Xi4[e];
        float4 z0r = Z0r4[e], z0i = Z0i4[e];
        float4 z1r = Z1r4[e], z1i = Z1i4[e];
        r0 += dot4(xrv, z0r) - dot4(xiv, z0i);
        s0 += dot4(xrv, z0i) + dot4(xiv, z0r);
        r1 += dot4(xrv, z1r) - dot4(xiv, z1i);
        s1 += dot4(xrv, z1i) + dot4(xiv, z1r);
    }
    #pragma unroll
    for (int off = 32; off > 0; off >>= 1) {
        r0 += __shfl_down(r0, off);
        s0 += __shfl_down(s0, off);
        r1 += __shfl_down(r1, off);
        s1 += __shfl_down(s1, off);
    }
    __shared__ float red[4][4];
    if ((tid & 63) == 0) {
        int wv = tid >> 6;
        red[wv][0] = r0; red[wv][1] = s0; red[wv][2] = r1; red[wv][3] = s1;
    }
    __syncthreads();
    if (tid == 0) {
        float a0 = red[0][0]+red[1][0]+red[2][0]+red[3][0];
        float a1 = red[0][1]+red[1][1]+red[2][1]+red[3][1];
        float a2 = red[0][2]+red[1][2]+red[2][2]+red[3][2];
        float a3 = red[0][3]+red[1][3]+red[2][3]+red[3][3];
        float* trp = ws + OFF_TR;
        trp[((q*2+0)*16 + b)*2 + 0] = a0;
        trp[((q*2+0)*16 + b)*2 + 1] = a1;
        trp[((q*2+1)*16 + b)*2 + 0] = a2;
        trp[((q*2+1)*16 + b)*2 + 1] = a3;
    }
}

// ---------------- Kernel 4: softmax over b for (q,kk) ----------------
__global__ __launch_bounds__(64) void k_softmax(float* __restrict__ ws) {
    const int t = threadIdx.x;      // 0..63 -> (q,kk)
    const float* trp = ws + OFF_TR + t*32;   // 16 b * 2
    float d[16];
    float mx = -1e30f;
    #pragma unroll
    for (int b = 0; b < 16; ++b) {
        float rr = trp[b*2+0], ii = trp[b*2+1];
        d[b] = sqrtf(rr*rr + ii*ii);
        mx = fmaxf(mx, d[b]);
    }
    float sum = 0.f;
    #pragma unroll
    for (int b = 0; b < 16; ++b) { d[b] = expf(d[b] - mx); sum += d[b]; }
    float inv = 1.f / sum;
    #pragma unroll
    for (int b = 0; b < 16; ++b) ws[OFF_S + t*16 + b] = d[b] * inv;
}

// ---------------- Kernel 5: broadcast output ----------------
__global__ __launch_bounds__(256) void k_out(const float* __restrict__ ws,
                                             float* __restrict__ out) {
    const int t = blockIdx.x >> 4, b = blockIdx.x & 15;
    const float s0 = ws[OFF_S + (t*2+0)*16 + b];
    const float s1 = ws[OFF_S + (t*2+1)*16 + b];
    const float4* Vr0 = (const float4*)(ws + OFF_VR + b*MAT);
    const float4* Vi0 = (const float4*)(ws + OFF_VI + b*MAT);
    const float4* Vr1 = (const float4*)(ws + OFF_VR + (16+b)*MAT);
    const float4* Vi1 = (const float4*)(ws + OFF_VI + (16+b)*MAT);
    float4* outR = (float4*)out + (t*16 + b)*4096;
    float4* outI = (float4*)out + 2097152 + (t*16 + b)*4096;
    #pragma unroll 4
    for (int w = 0; w < 16; ++w) {
        int e = w*256 + threadIdx.x;
        float4 a = Vr0[e], bb = Vi0[e], c = Vr1[e], dd = Vi1[e];
        outR[e] = make_float4(a.x*s0 + bb.x*s1, a.y*s0 + bb.y*s1,
                              a.z*s0 + bb.z*s1, a.w*s0 + bb.w*s1);
        outI[e] = make_float4(c.x*s0 + dd.x*s1, c.y*s0 + dd.y*s1,
                              c.z*s0 + dd.z*s1, c.w*s0 + dd.w*s1);
    }
}

extern "C" void kernel_launch(void* const* d_in, const int* in_sizes, int n_in,
                              void* d_out, int out_size, void* d_ws, size_t ws_size,
                              hipStream_t stream) {
    const float* xr = (const float*)d_in[0];
    const float* xi = (const float*)d_in[1];
    const float* Uq = (const float*)d_in[2];
    const float* Uk = (const float*)d_in[3];
    const float* Uv = (const float*)d_in[4];
    float* ws  = (float*)d_ws;
    float* out = (float*)d_out;

    k_M<<<128, 128, 0, stream>>>(Uq, Uk, Uv, ws);
    k_fused<<<512, 256, 0, stream>>>(xr, xi, Uv, ws);
    k_trace<<<512, 256, 0, stream>>>(xr, xi, ws);
    k_softmax<<<1, 64, 0, stream>>>(ws);
    k_out<<<512, 256, 0, stream>>>(ws, out);
}

// Round 11
// 97.066 us; speedup vs baseline: 1.2421x; 1.2421x over previous
//
#include <hip/hip_runtime.h>
#include <math.h>

// Problem constants
#define MAT 16384            // D*D
// Workspace float offsets
#define OFF_MC   0                        // M  interleaved [i][p][2]  (32768 f)
#define OFF_MTC  32768                    // M^T interleaved [k][j][2] (32768 f)
#define OFF_UVTC 65536                    // Uv^T interleaved [k][j][2]
#define OFF_ZSR  2129920                  // Zs = Z^T, [kk*16+b][j][i]
#define OFF_ZSI  (OFF_ZSR + 32*16384)
#define OFF_VR   (OFF_ZSI + 32*16384)     // V natural [t*16+b][i][j]
#define OFF_VI   (OFF_VR + 32*16384)
#define OFF_TR   (OFF_VI + 32*16384)      // tr[q][kk][b][2]
#define OFF_S    (OFF_TR + 2048)          // s[q][kk][b]

__device__ __forceinline__ float dot4(float4 a, float4 b) {
    return a.x*b.x + a.y*b.y + a.z*b.z + a.w*b.w;
}

// ---------------- Kernel 1: M = Uq^H * Uk + interleaved planes ----------------
__global__ __launch_bounds__(128) void k_M(const float* __restrict__ Uq,
                                           const float* __restrict__ Uk,
                                           const float* __restrict__ Uv,
                                           float* __restrict__ ws) {
    const int i = blockIdx.x;
    const int j = threadIdx.x;
    __shared__ float qr_s[128], qi_s[128];
    qr_s[j] = Uq[(j*128 + i)*2 + 0];   // Uq[p=j, i]
    qi_s[j] = Uq[(j*128 + i)*2 + 1];
    __syncthreads();
    const float2* Uk2 = (const float2*)Uk;
    float mr = 0.f, mi = 0.f;
    #pragma unroll 8
    for (int p = 0; p < 128; ++p) {
        float2 k2 = Uk2[p*128 + j];
        float qr = qr_s[p], qi = qi_s[p];
        mr += qr*k2.x + qi*k2.y;       // conj(Uq[p,i]) * Uk[p,j]
        mi += qr*k2.y - qi*k2.x;
    }
    ws[OFF_MC  + i*256 + 2*j]     = mr;   // M[i][j] interleaved
    ws[OFF_MC  + i*256 + 2*j + 1] = mi;
    ws[OFF_MTC + j*256 + 2*i]     = mr;   // MTC[k][j] = M[j][k]
    ws[OFF_MTC + j*256 + 2*i + 1] = mi;
    float2 uv = ((const float2*)Uv)[i*128 + j];
    ws[OFF_UVTC + j*256 + 2*i]     = uv.x; // UVTC[k][j] = Uv[j][k]
    ws[OFF_UVTC + j*256 + 2*i + 1] = uv.y;
}

// ---------------- Kernel 2: fused two-sided evolve Z = U X U^H (v6) ----------------
// grid 1024: m = bid&63 (XCD = m%8), strip i0 = (bid>>6)*8. Block 128 thr = 2 waves
// -> 4 blocks/CU (8 waves/CU). Wave w covers rows i0+4w..+3, all 128 cols, with a
// 2-way k-split: lane = cg + 32*kp handles cols 4cg..+3 at k = 2t+kp.
//  - A (U-strip / Y-strip) in LDS: 1-2 b128 per pp, 16-way multicast, conflict-free.
//  - B direct from L2 (zero lane duplication; X / UT planes L2-resident per XCD).
//  - k-half partial sums combined via __shfl_xor(32) once per phase.
// No barriers in the main loops; 2 at the interlude, 1 in the m<32 epilogue.
__global__ __launch_bounds__(128) void k_fused(const float* __restrict__ xr,
                                               const float* __restrict__ xi,
                                               const float* __restrict__ Uv,
                                               float* __restrict__ ws) {
    const int bid  = blockIdx.x;
    const int m    = bid & 63;
    const int i0   = (bid >> 6) * 8;
    const int tid  = threadIdx.x;       // 0..127
    const int w    = tid >> 6;          // wave: rows i0+4w .. i0+4w+3
    const int lane = tid & 63;
    const int cg   = lane & 31;         // cols 4cg..4cg+3
    const int kp   = lane >> 5;         // k-parity half

    __shared__ __align__(16) float At[2048];    // [k][w][r][2] : k*16 + w*8 + r*2
    __shared__ __align__(16) float Tb[2112];    // epilogue transpose [2][8][132]

    // ---- Stage A strip: rows i0..i0+7, all p (coalesced float2 loads) ----
    {
        const float2* Ap2 = (const float2*)((m < 32) ? (ws + OFF_MC) : Uv);
        #pragma unroll
        for (int rr = 0; rr < 8; ++rr) {
            float2 u = Ap2[(i0 + rr)*128 + tid];
            *(float2*)&At[tid*16 + (rr>>2)*8 + (rr&3)*2] = u;
        }
    }
    __syncthreads();

    // ================= Phase 1: Y = U * X =================
    float yr[4][4], yi[4][4];
    #pragma unroll
    for (int r = 0; r < 4; ++r)
        #pragma unroll
        for (int c = 0; c < 4; ++c) { yr[r][c] = 0.f; yi[r][c] = 0.f; }

    const float4* Xr4 = (const float4*)(xr + (m & 31)*MAT);
    const float4* Xi4 = (const float4*)(xi + (m & 31)*MAT);

    float4 pR0, pI0, pR1, pI1;
#define LDX(T, R, I) do { int _k = 2*(T) + kp;               \
    R = Xr4[_k*32 + cg]; I = Xi4[_k*32 + cg]; } while (0)

#define CFMA_P1(aLo, aHi, Rv, Iv) do {                                   \
    const float ar_[4] = {aLo.x, aLo.z, aHi.x, aHi.z};                   \
    const float ai_[4] = {aLo.y, aLo.w, aHi.y, aHi.w};                   \
    const float br_[4] = {Rv.x, Rv.y, Rv.z, Rv.w};                       \
    const float bi_[4] = {Iv.x, Iv.y, Iv.z, Iv.w};                       \
    _Pragma("unroll")                                                    \
    for (int r = 0; r < 4; ++r) {                                        \
        _Pragma("unroll")                                                \
        for (int c = 0; c < 4; ++c) {                                    \
            yr[r][c] += ar_[r]*br_[c] - ai_[r]*bi_[c];                   \
            yi[r][c] += ar_[r]*bi_[c] + ai_[r]*br_[c];                   \
        }                                                                \
    } } while (0)

    LDX(0, pR0, pI0);
    LDX(1, pR1, pI1);
    #pragma unroll 1
    for (int t = 0; t < 64; t += 2) {
        {
            int kk = 2*t + kp;
            float4 aLo = *(const float4*)&At[kk*16 + w*8];
            float4 aHi = *(const float4*)&At[kk*16 + w*8 + 4];
            CFMA_P1(aLo, aHi, pR0, pI0);
            int tn = (t+2 > 63) ? 63 : t+2; LDX(tn, pR0, pI0);
        }
        {
            int kk = 2*(t+1) + kp;
            float4 aLo = *(const float4*)&At[kk*16 + w*8];
            float4 aHi = *(const float4*)&At[kk*16 + w*8 + 4];
            CFMA_P1(aLo, aHi, pR1, pI1);
            int tn = (t+3 > 63) ? 63 : t+3; LDX(tn, pR1, pI1);
        }
    }

    // ================= Interlude: reduce k-halves, Y -> At =================
    #pragma unroll
    for (int r = 0; r < 4; ++r)
        #pragma unroll
        for (int c = 0; c < 4; ++c) {
            yr[r][c] += __shfl_xor(yr[r][c], 32);
            yi[r][c] += __shfl_xor(yi[r][c], 32);
        }
    __syncthreads();                      // all phase-1 At reads complete
    if (kp == 0) {
        #pragma unroll
        for (int c = 0; c < 4; ++c) {
            int col = 4*cg + c;
            *(float4*)&At[col*16 + w*8]     = make_float4(yr[0][c], yi[0][c], yr[1][c], yi[1][c]);
            *(float4*)&At[col*16 + w*8 + 4] = make_float4(yr[2][c], yi[2][c], yr[3][c], yi[3][c]);
        }
    }
    __syncthreads();                      // Yt visible

    // ================= Phase 2: Z = Y * U^H =================
    float zr[4][4], zi[4][4];
    #pragma unroll
    for (int r = 0; r < 4; ++r)
        #pragma unroll
        for (int c = 0; c < 4; ++c) { zr[r][c] = 0.f; zi[r][c] = 0.f; }

    const float4* UT4 = (const float4*)(ws + (m < 32 ? OFF_MTC : OFF_UVTC));

    float4 pE0, pO0, pE1, pO1;
#define LDU(T, E, O) do { int _k = 2*(T) + kp;               \
    E = UT4[_k*64 + 2*cg]; O = UT4[_k*64 + 2*cg + 1]; } while (0)

#define CFMA_P2(aLo, aHi, Ev, Ov) do {                                   \
    const float ya_[4] = {aLo.x, aLo.z, aHi.x, aHi.z};                   \
    const float yb_[4] = {aLo.y, aLo.w, aHi.y, aHi.w};                   \
    _Pragma("unroll")                                                    \
    for (int r = 0; r < 4; ++r) {                                        \
        const float yrv = ya_[r], yiv = yb_[r];                          \
        zr[r][0] += yrv*Ev.x + yiv*Ev.y;  zi[r][0] += yiv*Ev.x - yrv*Ev.y; \
        zr[r][1] += yrv*Ev.z + yiv*Ev.w;  zi[r][1] += yiv*Ev.z - yrv*Ev.w; \
        zr[r][2] += yrv*Ov.x + yiv*Ov.y;  zi[r][2] += yiv*Ov.x - yrv*Ov.y; \
        zr[r][3] += yrv*Ov.z + yiv*Ov.w;  zi[r][3] += yiv*Ov.z - yrv*Ov.w; \
    } } while (0)

    LDU(0, pE0, pO0);
    LDU(1, pE1, pO1);
    #pragma unroll 1
    for (int t = 0; t < 64; t += 2) {
        {
            int kk = 2*t + kp;
            float4 aLo = *(const float4*)&At[kk*16 + w*8];
            float4 aHi = *(const float4*)&At[kk*16 + w*8 + 4];
            CFMA_P2(aLo, aHi, pE0, pO0);
            int tn = (t+2 > 63) ? 63 : t+2; LDU(tn, pE0, pO0);
        }
        {
            int kk = 2*(t+1) + kp;
            float4 aLo = *(const float4*)&At[kk*16 + w*8];
            float4 aHi = *(const float4*)&At[kk*16 + w*8 + 4];
            CFMA_P2(aLo, aHi, pE1, pO1);
            int tn = (t+3 > 63) ? 63 : t+3; LDU(tn, pE1, pO1);
        }
    }

    // ---- reduce k-halves of Z ----
    #pragma unroll
    for (int r = 0; r < 4; ++r)
        #pragma unroll
        for (int c = 0; c < 4; ++c) {
            zr[r][c] += __shfl_xor(zr[r][c], 32);
            zi[r][c] += __shfl_xor(zi[r][c], 32);
        }

    // ================= Epilogue =================
    if (m < 32) {
        float* T_r = Tb;                  // [8][132]
        float* T_i = Tb + 1056;
        if (kp == 0) {
            #pragma unroll
            for (int r = 0; r < 4; ++r) {
                int ii = w*4 + r;
                *(float4*)&T_r[ii*132 + 4*cg] = make_float4(zr[r][0], zr[r][1], zr[r][2], zr[r][3]);
                *(float4*)&T_i[ii*132 + 4*cg] = make_float4(zi[r][0], zi[r][1], zi[r][2], zi[r][3]);
            }
        }
        __syncthreads();
        float* dstR = ws + OFF_ZSR + m*MAT;
        float* dstI = ws + OFF_ZSI + m*MAT;
        #pragma unroll
        for (int wl = 0; wl < 8; ++wl) {
            int o  = wl*128 + tid;        // 0..1023
            int c  = o >> 3;              // col j 0..127
            int ii = o & 7;               // row-in-strip
            dstR[c*128 + i0 + ii] = T_r[ii*132 + c];
            dstI[c*128 + i0 + ii] = T_i[ii*132 + c];
        }
    } else {
        if (kp == 0) {
            float* dstR = ws + OFF_VR + (m-32)*MAT;
            float* dstI = ws + OFF_VI + (m-32)*MAT;
            #pragma unroll
            for (int r = 0; r < 4; ++r) {
                int row = i0 + w*4 + r;
                *(float4*)&dstR[row*128 + 4*cg] = make_float4(zr[r][0], zr[r][1], zr[r][2], zr[r][3]);
                *(float4*)&dstI[row*128 + 4*cg] = make_float4(zi[r][0], zi[r][1], zi[r][2], zi[r][3]);
            }
        }
    }
#undef LDX
#undef LDU
#undef CFMA_P1
#undef CFMA_P2
}

// ---------------- Kernel 3: tr[q,kk,b] = sum X_qb .* Zs_kkb (complex) ----------------
__global__ __launch_bounds__(256) void k_trace(const float* __restrict__ xr,
                                               const float* __restrict__ xi,
                                               float* __restrict__ ws) {
    const int q = blockIdx.x >> 4, b = blockIdx.x & 15;
    const int tid = threadIdx.x;
    const float4* Xr4  = (const float4*)(xr + (q*16 + b)*MAT);
    const float4* Xi4  = (const float4*)(xi + (q*16 + b)*MAT);
    const float4* Z0r4 = (const float4*)(ws + OFF_ZSR + b*MAT);
    const float4* Z0i4 = (const float4*)(ws + OFF_ZSI + b*MAT);
    const float4* Z1r4 = (const float4*)(ws + OFF_ZSR + (16+b)*MAT);
    const float4* Z1i4 = (const float4*)(ws + OFF_ZSI + (16+b)*MAT);
    float r0 = 0.f, s0 = 0.f, r1 = 0.f, s1 = 0.f;
    #pragma unroll 4
    for (int w = 0; w < 16; ++w) {
        int e = w*256 + tid;
        float4 xrv = Xr4[e], xiv = Xi4[e];
        float4 z0r = Z0r4[e], z0i = Z0i4[e];
        float4 z1r = Z1r4[e], z1i = Z1i4[e];
        r0 += dot4(xrv, z0r) - dot4(xiv, z0i);
        s0 += dot4(xrv, z0i) + dot4(xiv, z0r);
        r1 += dot4(xrv, z1r) - dot4(xiv, z1i);
        s1 += dot4(xrv, z1i) + dot4(xiv, z1r);
    }
    #pragma unroll
    for (int off = 32; off > 0; off >>= 1) {
        r0 += __shfl_down(r0, off);
        s0 += __shfl_down(s0, off);
        r1 += __shfl_down(r1, off);
        s1 += __shfl_down(s1, off);
    }
    __shared__ float red[4][4];
    if ((tid & 63) == 0) {
        int wv = tid >> 6;
        red[wv][0] = r0; red[wv][1] = s0; red[wv][2] = r1; red[wv][3] = s1;
    }
    __syncthreads();
    if (tid == 0) {
        float a0 = red[0][0]+red[1][0]+red[2][0]+red[3][0];
        float a1 = red[0][1]+red[1][1]+red[2][1]+red[3][1];
        float a2 = red[0][2]+red[1][2]+red[2][2]+red[3][2];
        float a3 = red[0][3]+red[1][3]+red[2][3]+red[3][3];
        float* trp = ws + OFF_TR;
        trp[((q*2+0)*16 + b)*2 + 0] = a0;
        trp[((q*2+0)*16 + b)*2 + 1] = a1;
        trp[((q*2+1)*16 + b)*2 + 0] = a2;
        trp[((q*2+1)*16 + b)*2 + 1] = a3;
    }
}

// ---------------- Kernel 4: softmax over b for (q,kk) ----------------
__global__ __launch_bounds__(64) void k_softmax(float* __restrict__ ws) {
    const int t = threadIdx.x;      // 0..63 -> (q,kk)
    const float* trp = ws + OFF_TR + t*32;   // 16 b * 2
    float d[16];
    float mx = -1e30f;
    #pragma unroll
    for (int b = 0; b < 16; ++b) {
        float rr = trp[b*2+0], ii = trp[b*2+1];
        d[b] = sqrtf(rr*rr + ii*ii);
        mx = fmaxf(mx, d[b]);
    }
    float sum = 0.f;
    #pragma unroll
    for (int b = 0; b < 16; ++b) { d[b] = expf(d[b] - mx); sum += d[b]; }
    float inv = 1.f / sum;
    #pragma unroll
    for (int b = 0; b < 16; ++b) ws[OFF_S + t*16 + b] = d[b] * inv;
}

// ---------------- Kernel 5: broadcast output ----------------
__global__ __launch_bounds__(256) void k_out(const float* __restrict__ ws,
                                             float* __restrict__ out) {
    const int t = blockIdx.x >> 4, b = blockIdx.x & 15;
    const float s0 = ws[OFF_S + (t*2+0)*16 + b];
    const float s1 = ws[OFF_S + (t*2+1)*16 + b];
    const float4* Vr0 = (const float4*)(ws + OFF_VR + b*MAT);
    const float4* Vi0 = (const float4*)(ws + OFF_VI + b*MAT);
    const float4* Vr1 = (const float4*)(ws + OFF_VR + (16+b)*MAT);
    const float4* Vi1 = (const float4*)(ws + OFF_VI + (16+b)*MAT);
    float4* outR = (float4*)out + (t*16 + b)*4096;
    float4* outI = (float4*)out + 2097152 + (t*16 + b)*4096;
    #pragma unroll 4
    for (int w = 0; w < 16; ++w) {
        int e = w*256 + threadIdx.x;
        float4 a = Vr0[e], bb = Vi0[e], c = Vr1[e], dd = Vi1[e];
        outR[e] = make_float4(a.x*s0 + bb.x*s1, a.y*s0 + bb.y*s1,
                              a.z*s0 + bb.z*s1, a.w*s0 + bb.w*s1);
        outI[e] = make_float4(c.x*s0 + dd.x*s1, c.y*s0 + dd.y*s1,
                              c.z*s0 + dd.z*s1, c.w*s0 + dd.w*s1);
    }
}

extern "C" void kernel_launch(void* const* d_in, const int* in_sizes, int n_in,
                              void* d_out, int out_size, void* d_ws, size_t ws_size,
                              hipStream_t stream) {
    const float* xr = (const float*)d_in[0];
    const float* xi = (const float*)d_in[1];
    const float* Uq = (const float*)d_in[2];
    const float* Uk = (const float*)d_in[3];
    const float* Uv = (const float*)d_in[4];
    float* ws  = (float*)d_ws;
    float* out = (float*)d_out;

    k_M<<<128, 128, 0, stream>>>(Uq, Uk, Uv, ws);
    k_fused<<<1024, 128, 0, stream>>>(xr, xi, Uv, ws);
    k_trace<<<512, 256, 0, stream>>>(xr, xi, ws);
    k_softmax<<<1, 64, 0, stream>>>(ws);
    k_out<<<512, 256, 0, stream>>>(ws, out);
}